// Round 3
// baseline (359.759 us; speedup 1.0000x reference)
//
#include <hip/hip_runtime.h>
#include <stdint.h>

// MultiHeadAttentionProj: B=4, N=2048, D=512, H=8, HD=64
// cvtW(+maskprep fused) -> GEMM QKV (Q scaled 0.125*log2e) -> flash attn
// (32x32x16 MFMA, 8 waves = 4 q-groups x 2 key-halves over 128q x 128key
//  iteration tiles, in-register P via cvt_pk + v_permlane32_swap_b32,
//  XOR-swizzled conflict-free K/V LDS, lane-local rowsum, split-K epilogue)
// -> GEMM out. All LDS tiles use 128B rows + chunk^=(row&7) swizzle.

typedef __attribute__((ext_vector_type(8))) short short8;
typedef __attribute__((ext_vector_type(4))) short short4v;
typedef __attribute__((ext_vector_type(4))) float f32x4;
typedef __attribute__((ext_vector_type(16))) float f32x16;

#define DEV static __device__ __forceinline__

constexpr int Bc = 4, Nc = 2048, Dc = 512, Hc = 8, HDc = 64;
constexpr int Mc = Bc * Nc;        // 8192 rows
constexpr int QKVNc = 3 * Dc;      // 1536
constexpr float L2E = 1.44269504f;

DEV short bf16cast(float f) {      // f32 -> bf16 bits (RNE via HW cvt)
  return (short)__builtin_bit_cast(unsigned short, (__bf16)f);
}
DEV unsigned cvt_pk_bf16(float a, float b) {  // a->low16, b->high16 (RNE)
  unsigned short lb = __builtin_bit_cast(unsigned short, (__bf16)a);
  unsigned short hb = __builtin_bit_cast(unsigned short, (__bf16)b);
  return (unsigned)lb | ((unsigned)hb << 16);
}
DEV unsigned pack_shorts(short a, short b) {
  return (unsigned)(unsigned short)a | ((unsigned)(unsigned short)b << 16);
}
DEV short8 cvt8(float4 a, float4 b) {   // 8 f32 -> short8 bf16
  union { short8 s; uint4 u; } r;
  r.u.x = cvt_pk_bf16(a.x, a.y); r.u.y = cvt_pk_bf16(a.z, a.w);
  r.u.z = cvt_pk_bf16(b.x, b.y); r.u.w = cvt_pk_bf16(b.z, b.w);
  return r.s;
}
DEV float fast_exp2(float x) {
#if __has_builtin(__builtin_amdgcn_exp2f)
  return __builtin_amdgcn_exp2f(x);
#else
  return exp2f(x);
#endif
}
// v_permlane32_swap_b32: a[i>=32] <-> b[i-32]; turns (w0,w2) into frag words (0,2).
DEV void permswap(unsigned& a, unsigned& b) {
  asm volatile("v_permlane32_swap_b32 %0, %1" : "+v"(a), "+v"(b));
}

// Blocks 0..1023: convert Wq,Wk,Wv -> Wqkv (concat) and Wo -> Wob.
// Block 1024: maskprep (detect mask dtype, convert to additive floats).
__global__ void cvtw_kernel(const float* __restrict__ Wq, const float* __restrict__ Wk,
                            const float* __restrict__ Wv, const float* __restrict__ Wo,
                            short* __restrict__ Wqkv, short* __restrict__ Wob,
                            const void* __restrict__ mask, float* __restrict__ mf) {
  if (blockIdx.x == 1024) {                          // fused maskprep, 256 threads
    __shared__ int flag;
    if (threadIdx.x == 0) flag = 0;
    __syncthreads();
    const uchar4* m4 = (const uchar4*)mask;
    int acc = 0;
    for (int i = threadIdx.x; i < 2048; i += 256) {
      uchar4 v = m4[i];
      acc |= (int)v.y | (int)v.z | (int)v.w;
    }
    if (acc) atomicOr(&flag, 1);
    __syncthreads();
    int isbyte = flag;                               // int32 0/1 has bytes 1..3 zero
    for (int i = threadIdx.x; i < Bc * Nc; i += 256) {
      int v = isbyte ? (int)((const unsigned char*)mask)[i] : ((const int*)mask)[i];
      mf[i] = v ? -1e30f : 0.0f;
    }
    return;
  }
  int which = blockIdx.x >> 8;                       // 4 x 256 blocks
  int j = (blockIdx.x & 255) * 256 + threadIdx.x;    // float4 index < 65536
  const float* src = which == 0 ? Wq : which == 1 ? Wk : which == 2 ? Wv : Wo;
  short* dst = (which == 3) ? Wob : Wqkv + which * (Dc * Dc);
  float4 v = ((const float4*)src)[j];
  short4v o = { bf16cast(v.x), bf16cast(v.y), bf16cast(v.z), bf16cast(v.w) };
  ((short4v*)dst)[j] = o;
}

// C[M][N] = sum_k A[m][k]*Bm[n][k]. 128x128 tile, BK=64, 128B rows with
// chunk^(row&7) XOR swizzle (conflict-free b128 frag reads). Single-barrier
// double-buffered LDS; prefetch issued after the barrier.
template<bool A_F32, bool OUT_F32>
__global__ __launch_bounds__(256, 2) void gemm_bt(const void* __restrict__ Av,
                                                  const short* __restrict__ Bm,
                                                  void* __restrict__ Cv,
                                                  int M, int N, int K,
                                                  int qcols, float cscale) {
  __shared__ __align__(16) short At[2][128 * 64];
  __shared__ __align__(16) short Bt[2][128 * 64];
  const int tid = threadIdx.x, lane = tid & 63, wv = tid >> 6;
  const int quad = lane >> 4, l16 = lane & 15;
  const int mbase = blockIdx.y * 128, nbase = blockIdx.x * 128;
  const int wr = (wv >> 1) * 64, wc = (wv & 1) * 64;
  const float scale = (nbase < qcols) ? cscale : 1.0f;
  f32x4 acc[4][4] = {};
  float4 apf[4][2]; short8 aph[4], bpre[4];
#pragma unroll
  for (int i = 0; i < 4; i++) {                 // preload k0=0
    int flat = i * 256 + tid, row = flat >> 3, ch8 = (flat & 7) * 8;
    if (A_F32) {
      const float* Af = (const float*)Av;
      apf[i][0] = *(const float4*)&Af[(size_t)(mbase + row) * K + ch8];
      apf[i][1] = *(const float4*)&Af[(size_t)(mbase + row) * K + ch8 + 4];
    } else {
      aph[i] = *(const short8*)&((const short*)Av)[(size_t)(mbase + row) * K + ch8];
    }
    bpre[i] = *(const short8*)&Bm[(size_t)(nbase + row) * K + ch8];
  }
  for (int k0 = 0; k0 < K; k0 += 64) {
    const int cur = (k0 >> 6) & 1;
#pragma unroll
    for (int i = 0; i < 4; i++) {               // regs -> LDS (swizzled chunk)
      int flat = i * 256 + tid, row = flat >> 3, c = flat & 7;
      int idx = row * 64 + (((c ^ (row & 7))) << 3);
      *(short8*)&At[cur][idx] = A_F32 ? cvt8(apf[i][0], apf[i][1]) : aph[i];
      *(short8*)&Bt[cur][idx] = bpre[i];
    }
    __syncthreads();
    if (k0 + 64 < K) {                          // issue next-tile loads
#pragma unroll
      for (int i = 0; i < 4; i++) {
        int flat = i * 256 + tid, row = flat >> 3, ch8 = (flat & 7) * 8;
        if (A_F32) {
          const float* Af = (const float*)Av;
          apf[i][0] = *(const float4*)&Af[(size_t)(mbase + row) * K + k0 + 64 + ch8];
          apf[i][1] = *(const float4*)&Af[(size_t)(mbase + row) * K + k0 + 64 + ch8 + 4];
        } else {
          aph[i] = *(const short8*)&((const short*)Av)[(size_t)(mbase + row) * K + k0 + 64 + ch8];
        }
        bpre[i] = *(const short8*)&Bm[(size_t)(nbase + row) * K + k0 + 64 + ch8];
      }
    }
#pragma unroll
    for (int s = 0; s < 2; s++) {
      const int sw = ((quad + 4 * s) ^ (l16 & 7)) << 3;   // same for all t
      short8 af[4], bf[4];
#pragma unroll
      for (int t = 0; t < 4; t++) {
        af[t] = *(short8*)&At[cur][(wr + t * 16 + l16) * 64 + sw];
        bf[t] = *(short8*)&Bt[cur][(wc + t * 16 + l16) * 64 + sw];
      }
#pragma unroll
      for (int mt = 0; mt < 4; mt++)
#pragma unroll
        for (int nt = 0; nt < 4; nt++)
          acc[mt][nt] = __builtin_amdgcn_mfma_f32_16x16x32_bf16(af[mt], bf[nt], acc[mt][nt], 0, 0, 0);
    }
    __syncthreads();
  }
#pragma unroll
  for (int mt = 0; mt < 4; mt++)
#pragma unroll
    for (int nt = 0; nt < 4; nt++)
#pragma unroll
      for (int r = 0; r < 4; r++) {             // C/D: row=quad*4+r, col=l16
        int row = mbase + wr + mt * 16 + quad * 4 + r;
        int col = nbase + wc + nt * 16 + l16;
        float v = acc[mt][nt][r] * scale;
        if (OUT_F32) ((float*)Cv)[(size_t)row * N + col] = v;
        else         ((short*)Cv)[(size_t)row * N + col] = bf16cast(v);
      }
}

// Flash attention, 32x32x16 MFMA. 512 threads = 8 waves: wave wv handles
// q-group (wv&3)*32 and key-half (wv>>2)*64 of each 128-key tile; the two
// key-halves' partial O/rowsum add in the epilogue (no-max softmax).
// P stays in registers: swapped QK^T (lane = q col) -> exp2 -> cvt_pk ->
// permlane32_swap -> PV A-frags. K/V LDS: 128B rows, chunk ^= (row&7).
__global__ __launch_bounds__(512, 4) void attn_kernel(const short* __restrict__ QKV,
                                                      const float* __restrict__ bias,
                                                      const float* __restrict__ maskf,
                                                      short* __restrict__ Aout) {
  __shared__ __align__(16) unsigned char smem[73728];
  // [0,32K)=Kt dbuf [128key][64hd], [32K,64K)=Vt dbuf [64hd][128key],
  // [64K,72K)=mask floats. Epilogue: [0,34K)=partials, [64K,+512)=rowsums.
  short* KtB = (short*)smem;
  short* VtB = (short*)(smem + 32768);
  float* mlds = (float*)(smem + 65536);

  const int tid = threadIdx.x, lane = tid & 63, wv = tid >> 6;
  const int h = lane >> 5, l31 = lane & 31;
  const int wq = wv & 3, wsel = wv >> 2;
  const int qt = blockIdx.x & 15, hd0 = ((blockIdx.x >> 4) & 7) * HDc;
  const int b = (int)(blockIdx.x >> 7);
  const int qrow0 = qt * 128;
  const int qglob = qrow0 + wq * 32 + l31;
  const float* biasrow = bias + ((size_t)b * Nc + qglob) * Nc;

  ((float4*)mlds)[tid] = ((const float4*)(maskf + b * Nc))[tid];   // 2048 floats

  short8 qf[4];  // Q (pre-scaled 0.125*log2e): lane q=l31, hd = 16s + 8h + j
  {
    const short* qp = QKV + (size_t)(b * Nc + qglob) * QKVNc + hd0 + 8 * h;
    qf[0] = *(const short8*)qp;        qf[1] = *(const short8*)(qp + 16);
    qf[2] = *(const short8*)(qp + 32); qf[3] = *(const short8*)(qp + 48);
  }

  const short* Kbase = QKV + Dc + hd0;
  const short* Vbase = QKV + 2 * Dc + hd0;
  const int kr = tid >> 2, kc2 = (tid & 3) * 2;      // K: row kr, chunks kc2,kc2+1
  const int vp = tid & 63, vq = wv;                  // V: keys 2vp..+1, hd oct vq

  short8 kpre0, kpre1, v0pre, v1pre;
  kpre0 = *(const short8*)&Kbase[(size_t)(b * Nc + kr) * QKVNc + kc2 * 8];
  kpre1 = *(const short8*)&Kbase[(size_t)(b * Nc + kr) * QKVNc + kc2 * 8 + 8];
  v0pre = *(const short8*)&Vbase[(size_t)(b * Nc + 2 * vp) * QKVNc + vq * 8];
  v1pre = *(const short8*)&Vbase[(size_t)(b * Nc + 2 * vp + 1) * QKVNc + vq * 8];

  f32x16 oacc[2] = {};                               // O: col hd=32t+l31, row q
  float rs = 0.f;

  for (int kt = 0; kt < 16; ++kt) {
    const int cur = kt & 1;
    const int kb = kt << 7;
    const int kbn = ((kt + 1) & 15) << 7;
    short* Ktc = KtB + cur * 8192;
    short* Vtc = VtB + cur * 8192;

    // stage regs -> LDS[cur], swizzled
    *(short8*)&Ktc[kr * 64 + ((kc2 ^ (kr & 7)) << 3)] = kpre0;
    *(short8*)&Ktc[kr * 64 + (((kc2 + 1) ^ (kr & 7)) << 3)] = kpre1;
#pragma unroll
    for (int j = 0; j < 8; ++j) {
      int hd = 8 * vq + j;
      *(unsigned*)&Vtc[hd * 128 + (((vp >> 2) ^ (hd & 7)) << 3) + ((vp & 3) << 1)] =
          pack_shorts(v0pre[j], v1pre[j]);
    }
    __syncthreads();

    // prefetch next tile (drains at next iteration's barrier)
    kpre0 = *(const short8*)&Kbase[(size_t)(b * Nc + kbn + kr) * QKVNc + kc2 * 8];
    kpre1 = *(const short8*)&Kbase[(size_t)(b * Nc + kbn + kr) * QKVNc + kc2 * 8 + 8];
    v0pre = *(const short8*)&Vbase[(size_t)(b * Nc + kbn + 2 * vp) * QKVNc + vq * 8];
    v1pre = *(const short8*)&Vbase[(size_t)(b * Nc + kbn + 2 * vp + 1) * QKVNc + vq * 8];

    const int keyb = kb + wsel * 64;                 // this wave's 64-key window

    // ---- key-tile 0 (local keys 0..31) ----
    float4 bb0[4];
#pragma unroll
    for (int m = 0; m < 4; ++m) bb0[m] = *(const float4*)&biasrow[keyb + 8 * m + 4 * h];
    f32x16 s0;
#pragma unroll
    for (int m = 0; m < 4; ++m) {                    // C-init = mask
      float4 mv = *(const float4*)&mlds[keyb + 8 * m + 4 * h];
      s0[4 * m + 0] = mv.x; s0[4 * m + 1] = mv.y; s0[4 * m + 2] = mv.z; s0[4 * m + 3] = mv.w;
    }
    {
      const int row = wsel * 64 + l31, rx = row & 7;
      const short* kp = &Ktc[row * 64];
#pragma unroll
      for (int s = 0; s < 4; ++s) {
        short8 kf = *(const short8*)&kp[((2 * s + h) ^ rx) << 3];
        s0 = __builtin_amdgcn_mfma_f32_32x32x16_bf16(kf, qf[s], s0, 0, 0, 0);
      }
    }

    // ---- key-tile 1 (local keys 32..63) ----
    float4 bb1[4];
#pragma unroll
    for (int m = 0; m < 4; ++m) bb1[m] = *(const float4*)&biasrow[keyb + 32 + 8 * m + 4 * h];
    f32x16 s1;
#pragma unroll
    for (int m = 0; m < 4; ++m) {
      float4 mv = *(const float4*)&mlds[keyb + 32 + 8 * m + 4 * h];
      s1[4 * m + 0] = mv.x; s1[4 * m + 1] = mv.y; s1[4 * m + 2] = mv.z; s1[4 * m + 3] = mv.w;
    }
    {
      const int row = wsel * 64 + 32 + l31, rx = row & 7;
      const short* kp = &Ktc[row * 64];
#pragma unroll
      for (int s = 0; s < 4; ++s) {
        short8 kf = *(const short8*)&kp[((2 * s + h) ^ rx) << 3];
        s1 = __builtin_amdgcn_mfma_f32_32x32x16_bf16(kf, qf[s], s1, 0, 0, 0);
      }
    }

    // ---- softmax (no-max): p = exp2(s + bias*log2e [+mask]) ----
    unsigned pk0[8], pk1[8];
#pragma unroll
    for (int m = 0; m < 4; ++m) {
      float e0 = fast_exp2(__builtin_fmaf(bb0[m].x, L2E, s0[4 * m + 0]));
      float e1 = fast_exp2(__builtin_fmaf(bb0[m].y, L2E, s0[4 * m + 1]));
      float e2 = fast_exp2(__builtin_fmaf(bb0[m].z, L2E, s0[4 * m + 2]));
      float e3 = fast_exp2(__builtin_fmaf(bb0[m].w, L2E, s0[4 * m + 3]));
      rs += (e0 + e1) + (e2 + e3);
      pk0[2 * m] = cvt_pk_bf16(e0, e1);
      pk0[2 * m + 1] = cvt_pk_bf16(e2, e3);
    }
#pragma unroll
    for (int m = 0; m < 4; ++m) {
      float e0 = fast_exp2(__builtin_fmaf(bb1[m].x, L2E, s1[4 * m + 0]));
      float e1 = fast_exp2(__builtin_fmaf(bb1[m].y, L2E, s1[4 * m + 1]));
      float e2 = fast_exp2(__builtin_fmaf(bb1[m].z, L2E, s1[4 * m + 2]));
      float e3 = fast_exp2(__builtin_fmaf(bb1[m].w, L2E, s1[4 * m + 3]));
      rs += (e0 + e1) + (e2 + e3);
      pk1[2 * m] = cvt_pk_bf16(e0, e1);
      pk1[2 * m + 1] = cvt_pk_bf16(e2, e3);
    }
    // redistribute P across lane halves -> A-frags (keys 16u+8h+{0..7})
    permswap(pk0[0], pk0[2]); permswap(pk0[1], pk0[3]);
    permswap(pk0[4], pk0[6]); permswap(pk0[5], pk0[7]);
    permswap(pk1[0], pk1[2]); permswap(pk1[1], pk1[3]);
    permswap(pk1[4], pk1[6]); permswap(pk1[5], pk1[7]);
    union { unsigned u[4]; short8 s; } pa0{{pk0[0], pk0[1], pk0[2], pk0[3]}},
                                       pa1{{pk0[4], pk0[5], pk0[6], pk0[7]}},
                                       pa2{{pk1[0], pk1[1], pk1[2], pk1[3]}},
                                       pa3{{pk1[4], pk1[5], pk1[6], pk1[7]}};

    // ---- PV: O[t] += P · V, contracting the wave's 64 keys ----
#pragma unroll
    for (int t = 0; t < 2; ++t) {
      const int hdr = 32 * t + l31, rx = hdr & 7;
      const short* vpq = &Vtc[hdr * 128];
      short8 vf0 = *(const short8*)&vpq[((8 * wsel + 0 + h) ^ rx) << 3];
      short8 vf1 = *(const short8*)&vpq[((8 * wsel + 2 + h) ^ rx) << 3];
      short8 vf2 = *(const short8*)&vpq[((8 * wsel + 4 + h) ^ rx) << 3];
      short8 vf3 = *(const short8*)&vpq[((8 * wsel + 6 + h) ^ rx) << 3];
      oacc[t] = __builtin_amdgcn_mfma_f32_32x32x16_bf16(pa0.s, vf0, oacc[t], 0, 0, 0);
      oacc[t] = __builtin_amdgcn_mfma_f32_32x32x16_bf16(pa1.s, vf1, oacc[t], 0, 0, 0);
      oacc[t] = __builtin_amdgcn_mfma_f32_32x32x16_bf16(pa2.s, vf2, oacc[t], 0, 0, 0);
      oacc[t] = __builtin_amdgcn_mfma_f32_32x32x16_bf16(pa3.s, vf3, oacc[t], 0, 0, 0);
    }
  }

  // ---- epilogue: combine key-halves (wv <-> wv+4), normalize, store ----
  rs += __shfl_xor(rs, 32);                          // both lane halves: full 64-key sum
  __syncthreads();                                   // LDS tiles dead; reuse as scratch
  float* scr = (float*)smem;                         // [4][64][34]
  if (wv >= 4) {
    float* p = scr + ((size_t)(wv - 4) * 64 + lane) * 34;
#pragma unroll
    for (int r = 0; r < 16; ++r) { p[r] = oacc[0][r]; p[16 + r] = oacc[1][r]; }
    p[32] = rs;
  }
  __syncthreads();
  if (wv < 4) {
    const float* p = scr + ((size_t)wv * 64 + lane) * 34;
#pragma unroll
    for (int r = 0; r < 16; ++r) { oacc[0][r] += p[r]; oacc[1][r] += p[16 + r]; }
    rs += p[32];
    float* rsum = (float*)(smem + 65536);            // 128 floats (mask area, dead)
    if (lane < 32) rsum[wv * 32 + l31] = rs;         // same-wave produce/consume
#pragma unroll
    for (int r = 0; r < 16; ++r) {
      int q = (r & 3) + 8 * (r >> 2) + 4 * h;        // C row
      float inv = 1.0f / rsum[wv * 32 + q];
      size_t row = (size_t)(b * Nc + qrow0 + wq * 32 + q);
      Aout[row * Dc + hd0 + l31]      = bf16cast(oacc[0][r] * inv);
      Aout[row * Dc + hd0 + 32 + l31] = bf16cast(oacc[1][r] * inv);
    }
  }
}

extern "C" void kernel_launch(void* const* d_in, const int* in_sizes, int n_in,
                              void* d_out, int out_size, void* d_ws, size_t ws_size,
                              hipStream_t stream) {
  const float* q    = (const float*)d_in[0];
  const void*  mask = d_in[1];
  const float* bias = (const float*)d_in[2];
  const float* Wq   = (const float*)d_in[3];
  const float* Wk   = (const float*)d_in[4];
  const float* Wv   = (const float*)d_in[5];
  const float* Wo   = (const float*)d_in[6];
  float* out = (float*)d_out;

  char* ws = (char*)d_ws;
  short* Wqkv = (short*)ws;  ws += (size_t)QKVNc * Dc * 2;
  short* Wob  = (short*)ws;  ws += (size_t)Dc * Dc * 2;
  float* mf   = (float*)ws;  ws += (size_t)Bc * Nc * 4;
  short* QKV  = (short*)ws;  ws += (size_t)Mc * QKVNc * 2;
  short* aout = (short*)ws;  ws += (size_t)Mc * Dc * 2;

  cvtw_kernel<<<dim3(1025), dim3(256), 0, stream>>>(Wq, Wk, Wv, Wo, Wqkv, Wob, mask, mf);

  // Q pre-scaled by 0.125*log2e so attn can use exp2 directly.
  gemm_bt<true, false><<<dim3(QKVNc / 128, Mc / 128), dim3(256), 0, stream>>>(
      (const void*)q, Wqkv, (void*)QKV, Mc, QKVNc, Dc, Dc, 0.125f * L2E);
  attn_kernel<<<dim3(Bc * Hc * 16), dim3(512), 0, stream>>>(QKV, bias, mf, aout);
  gemm_bt<false, true><<<dim3(Dc / 128, Mc / 128), dim3(256), 0, stream>>>(
      (const void*)aout, Wob, (void*)out, Mc, Dc, Dc, 0, 1.0f);
}

// Round 4
// 276.911 us; speedup vs baseline: 1.2992x; 1.2992x over previous
//
#include <hip/hip_runtime.h>
#include <stdint.h>

// MultiHeadAttentionProj: B=4, N=2048, D=512, H=8, HD=64
// cvtW(+maskprep fused) -> GEMM QKV (single-buffer 2-barrier, verified-fast)
// -> flash attn (BM=128, 8 waves, S^T form, exp2 softmax folded into MFMA
//    C-init, rowsum via MFMA, single-barrier dbuf K/V LDS at pitch 64 with
//    chunk^=(row&7) swizzle, P kept in registers via 4x v_permlane32_swap +
//    static V key-permutation (bits 3<->2) so PV contracts in permuted order)
// -> GEMM out.

typedef __attribute__((ext_vector_type(8))) short short8;
typedef __attribute__((ext_vector_type(4))) short short4v;
typedef __attribute__((ext_vector_type(4))) float f32x4;

#define DEV static __device__ __forceinline__

constexpr int Bc = 4, Nc = 2048, Dc = 512, Hc = 8, HDc = 64;
constexpr int Mc = Bc * Nc;        // 8192 rows
constexpr int QKVNc = 3 * Dc;      // 1536
constexpr float L2E = 1.44269504f;

DEV short bf16cast(float f) {      // f32 -> bf16 bits (RNE via HW cvt)
  return (short)__builtin_bit_cast(unsigned short, (__bf16)f);
}
DEV unsigned cvt_pk_bf16(float a, float b) {  // a->low16, b->high16 (RNE)
  unsigned short lb = __builtin_bit_cast(unsigned short, (__bf16)a);
  unsigned short hb = __builtin_bit_cast(unsigned short, (__bf16)b);
  return (unsigned)lb | ((unsigned)hb << 16);
}
DEV unsigned pack_shorts(short a, short b) {
  return (unsigned)(unsigned short)a | ((unsigned)(unsigned short)b << 16);
}
DEV short8 cvt8(float4 a, float4 b) {   // 8 f32 -> short8 bf16
  union { short8 s; uint4 u; } r;
  r.u.x = cvt_pk_bf16(a.x, a.y); r.u.y = cvt_pk_bf16(a.z, a.w);
  r.u.z = cvt_pk_bf16(b.x, b.y); r.u.w = cvt_pk_bf16(b.z, b.w);
  return r.s;
}
DEV float fast_exp2(float x) {
#if __has_builtin(__builtin_amdgcn_exp2f)
  return __builtin_amdgcn_exp2f(x);
#else
  return exp2f(x);
#endif
}
// HW-verified (R3 passing run): after op, a = [a.lo32, b.lo32], b = [a.hi32, b.hi32]
DEV void permswap32(unsigned& a, unsigned& b) {
  asm volatile("v_permlane32_swap_b32 %0, %1" : "+v"(a), "+v"(b));
}

// Blocks 0..1023: convert Wq,Wk,Wv -> Wqkv (concat) and Wo -> Wob.
// Block 1024: maskprep (detect mask dtype, convert to additive floats).
__global__ void cvtw_kernel(const float* __restrict__ Wq, const float* __restrict__ Wk,
                            const float* __restrict__ Wv, const float* __restrict__ Wo,
                            short* __restrict__ Wqkv, short* __restrict__ Wob,
                            const void* __restrict__ mask, float* __restrict__ mf) {
  if (blockIdx.x == 1024) {                          // fused maskprep, 256 threads
    __shared__ int flag;
    if (threadIdx.x == 0) flag = 0;
    __syncthreads();
    const uchar4* m4 = (const uchar4*)mask;
    int acc = 0;
    for (int i = threadIdx.x; i < 2048; i += 256) {
      uchar4 v = m4[i];
      acc |= (int)v.y | (int)v.z | (int)v.w;
    }
    if (acc) atomicOr(&flag, 1);
    __syncthreads();
    int isbyte = flag;                               // int32 0/1 has bytes 1..3 zero
    for (int i = threadIdx.x; i < Bc * Nc; i += 256) {
      int v = isbyte ? (int)((const unsigned char*)mask)[i] : ((const int*)mask)[i];
      mf[i] = v ? -1e30f : 0.0f;
    }
    return;
  }
  int which = blockIdx.x >> 8;                       // 4 x 256 blocks
  int j = (blockIdx.x & 255) * 256 + threadIdx.x;    // float4 index < 65536
  const float* src = which == 0 ? Wq : which == 1 ? Wk : which == 2 ? Wv : Wo;
  short* dst = (which == 3) ? Wob : Wqkv + which * (Dc * Dc);
  float4 v = ((const float4*)src)[j];
  short4v o = { bf16cast(v.x), bf16cast(v.y), bf16cast(v.z), bf16cast(v.w) };
  ((short4v*)dst)[j] = o;
}

// C[M][N] = sum_k A[m][k]*Bm[n][k]. 128x128 tile, BK=64, rows padded to 72
// shorts; reg-prefetch pipeline. (R0/R1-verified version: single buffer.)
template<bool A_F32, bool OUT_F32>
__global__ __launch_bounds__(256, 2) void gemm_bt(const void* __restrict__ Av,
                                                  const short* __restrict__ Bm,
                                                  void* __restrict__ Cv,
                                                  int M, int N, int K,
                                                  int qcols, float cscale) {
  __shared__ __align__(16) short At[128 * 72];
  __shared__ __align__(16) short Bt[128 * 72];
  const int tid = threadIdx.x, lane = tid & 63, wv = tid >> 6;
  const int quad = lane >> 4, l16 = lane & 15;
  const int mbase = blockIdx.y * 128, nbase = blockIdx.x * 128;
  const int wr = (wv >> 1) * 64, wc = (wv & 1) * 64;
  const float scale = (nbase < qcols) ? cscale : 1.0f;
  f32x4 acc[4][4] = {};
  float4 apf[4][2]; short8 aph[4], bpre[4];
#pragma unroll
  for (int i = 0; i < 4; i++) {                 // preload k0=0
    int flat = i * 256 + tid, row = flat >> 3, ch8 = (flat & 7) * 8;
    if (A_F32) {
      const float* Af = (const float*)Av;
      apf[i][0] = *(const float4*)&Af[(size_t)(mbase + row) * K + ch8];
      apf[i][1] = *(const float4*)&Af[(size_t)(mbase + row) * K + ch8 + 4];
    } else {
      aph[i] = *(const short8*)&((const short*)Av)[(size_t)(mbase + row) * K + ch8];
    }
    bpre[i] = *(const short8*)&Bm[(size_t)(nbase + row) * K + ch8];
  }
  for (int k0 = 0; k0 < K; k0 += 64) {
    __syncthreads();
#pragma unroll
    for (int i = 0; i < 4; i++) {
      int flat = i * 256 + tid, row = flat >> 3, ch8 = (flat & 7) * 8;
      *(short8*)&At[row * 72 + ch8] = A_F32 ? cvt8(apf[i][0], apf[i][1]) : aph[i];
      *(short8*)&Bt[row * 72 + ch8] = bpre[i];
    }
    if (k0 + 64 < K) {
#pragma unroll
      for (int i = 0; i < 4; i++) {             // prefetch next tile
        int flat = i * 256 + tid, row = flat >> 3, ch8 = (flat & 7) * 8;
        if (A_F32) {
          const float* Af = (const float*)Av;
          apf[i][0] = *(const float4*)&Af[(size_t)(mbase + row) * K + k0 + 64 + ch8];
          apf[i][1] = *(const float4*)&Af[(size_t)(mbase + row) * K + k0 + 64 + ch8 + 4];
        } else {
          aph[i] = *(const short8*)&((const short*)Av)[(size_t)(mbase + row) * K + k0 + 64 + ch8];
        }
        bpre[i] = *(const short8*)&Bm[(size_t)(nbase + row) * K + k0 + 64 + ch8];
      }
    }
    __syncthreads();
#pragma unroll
    for (int s = 0; s < 2; s++) {
      short8 af[4], bf[4];
#pragma unroll
      for (int t = 0; t < 4; t++) {
        af[t] = *(short8*)&At[(wr + t * 16 + l16) * 72 + quad * 8 + s * 32];
        bf[t] = *(short8*)&Bt[(wc + t * 16 + l16) * 72 + quad * 8 + s * 32];
      }
#pragma unroll
      for (int mt = 0; mt < 4; mt++)
#pragma unroll
        for (int nt = 0; nt < 4; nt++)
          acc[mt][nt] = __builtin_amdgcn_mfma_f32_16x16x32_bf16(af[mt], bf[nt], acc[mt][nt], 0, 0, 0);
    }
  }
#pragma unroll
  for (int mt = 0; mt < 4; mt++)
#pragma unroll
    for (int nt = 0; nt < 4; nt++)
#pragma unroll
      for (int r = 0; r < 4; r++) {             // C/D: row=quad*4+r, col=l16
        int row = mbase + wr + mt * 16 + quad * 4 + r;
        int col = nbase + wc + nt * 16 + l16;
        float v = acc[mt][nt][r] * scale;
        if (OUT_F32) ((float*)Cv)[(size_t)row * N + col] = v;
        else         ((short*)Cv)[(size_t)row * N + col] = bf16cast(v);
      }
}

// Flash attention, S^T form. BM=128 q-rows, 512 threads (8 waves x 16 q-rows),
// 64-key tiles, single-barrier double-buffered K/V LDS (pitch 64, chunk XOR
// swizzle). Softmax: C-init = bias*log2e + mask (Q pre-scaled 0.125*log2e)
// -> p = exp2(S'). P never touches LDS: cvt_pk pairs + 4x permlane32_swap
// deliver the A-frag; the leftover bit-swap (key bits 3<->2) is absorbed into
// V's LDS column permutation so P and V contract in the same permuted order.
// Row-sum via MFMA against all-ones B (order-independent).
__global__ __launch_bounds__(512, 2) void attn_kernel(const short* __restrict__ QKV,
                                                      const float* __restrict__ bias,
                                                      const float* __restrict__ maskf,
                                                      short* __restrict__ Aout) {
  __shared__ __align__(16) short Kt[2][64 * 64];     // [key][hd], dbuf, swizzled
  __shared__ __align__(16) short Vt[2][64 * 64];     // [hd][key_pos], dbuf, swizzled
  __shared__ __align__(16) float mlds[Nc];
  const int tid = threadIdx.x, lane = tid & 63, wv = tid >> 6;   // wv 0..7
  const int quad = lane >> 4, l16 = lane & 15;
  const int qt = blockIdx.x & 15, h = (blockIdx.x >> 4) & 7, b = (int)(blockIdx.x >> 7);
  const int qrow0 = qt * 128;
  const int qglob = qrow0 + wv * 16 + l16;
  const float* biasrow = bias + ((size_t)b * Nc + qglob) * Nc;

  ((float4*)mlds)[tid] = ((const float4*)(maskf + b * Nc))[tid];  // 2048 floats

  short8 qf[2];  // Q frag (pre-scaled 0.125*log2e): [q=l16][k=quad*8+j (+32s)]
  {
    const short* qp = QKV + (size_t)(b * Nc + qglob) * QKVNc + h * HDc + quad * 8;
    qf[0] = *(const short8*)qp;
    qf[1] = *(const short8*)(qp + 32);
  }

  const int vp = tid & 31, vq = tid >> 5;            // key-pair 0..31, hd-quad 0..15
  // V column permutation: swap key-pair bits 2<->1 (key bits 3<->2).
  const int vperm = (vp & 25) | ((vp & 4) >> 1) | ((vp & 2) << 1);
  const int krow = tid >> 3, kchunk = tid & 7;       // K staging: 1 short8/thread
  const int kwofs = krow * 64 + ((kchunk ^ (krow & 7)) << 3);
  const short* Kbase = QKV + Dc + h * HDc;
  const short* Vbase = QKV + 2 * Dc + h * HDc;

  short8 kpre; short4v v0pre, v1pre; float4 bpre[4];
  kpre  = *(const short8*)&Kbase[(size_t)(b * Nc + krow) * QKVNc + kchunk * 8];
  v0pre = *(const short4v*)&Vbase[(size_t)(b * Nc + 2 * vp) * QKVNc + 4 * vq];
  v1pre = *(const short4v*)&Vbase[(size_t)(b * Nc + 2 * vp + 1) * QKVNc + 4 * vq];
#pragma unroll
  for (int t = 0; t < 4; t++) bpre[t] = *(const float4*)&biasrow[t * 16 + quad * 4];

  const short ONEB = (short)0x3F80;                  // bf16 1.0
  const short8 ones = { ONEB, ONEB, ONEB, ONEB, ONEB, ONEB, ONEB, ONEB };

  f32x4 oacc[4] = {};
  f32x4 sumacc = {};                                 // row-sum of P, rows = quad*4+r

  for (int kt = 0; kt < 32; kt++) {
    const int cur = kt & 1;
    const int kb = kt * 64;
    const int kbn = ((kt + 1) & 31) * 64;            // next tile (wraps, in-bounds)

    // W: regs -> LDS buf[cur] (swizzled)
    *(short8*)&Kt[cur][kwofs] = kpre;
#pragma unroll
    for (int j = 0; j < 4; j++) {                    // V -> LDS transposed (b32)
      int hd = 4 * vq + j;
      *(unsigned*)&Vt[cur][hd * 64 + (((vperm >> 2) ^ (hd & 7)) << 3) + 2 * (vperm & 3)] =
          pack_shorts(v0pre[j], v1pre[j]);
    }
    __syncthreads();                                 // ONE barrier per tile

    // C-init consumes bpre BEFORE prefetch overwrites it (no bcur copy)
    f32x4 sacc[4];                                   // C-init = bias*log2e + mask
#pragma unroll
    for (int t = 0; t < 4; t++) {
      float4 mv = *(const float4*)&mlds[kb + t * 16 + quad * 4];
      sacc[t][0] = __builtin_fmaf(bpre[t].x, L2E, mv.x);
      sacc[t][1] = __builtin_fmaf(bpre[t].y, L2E, mv.y);
      sacc[t][2] = __builtin_fmaf(bpre[t].z, L2E, mv.z);
      sacc[t][3] = __builtin_fmaf(bpre[t].w, L2E, mv.w);
    }

    // L: issue next-tile loads; drained at NEXT iteration's barrier
    kpre  = *(const short8*)&Kbase[(size_t)(b * Nc + kbn + krow) * QKVNc + kchunk * 8];
    v0pre = *(const short4v*)&Vbase[(size_t)(b * Nc + kbn + 2 * vp) * QKVNc + 4 * vq];
    v1pre = *(const short4v*)&Vbase[(size_t)(b * Nc + kbn + 2 * vp + 1) * QKVNc + 4 * vq];
#pragma unroll
    for (int t = 0; t < 4; t++) bpre[t] = *(const float4*)&biasrow[kbn + t * 16 + quad * 4];

    // QK^T: S^T[key=16t+4quad+r][q=l16]
#pragma unroll
    for (int s = 0; s < 2; s++)
#pragma unroll
      for (int t = 0; t < 4; t++) {                  // A=K frag (m=key), B=Q frag (n=q)
        short8 kf = *(short8*)&Kt[cur][(t * 16 + l16) * 64 + (((quad + 4 * s) ^ (l16 & 7)) << 3)];
        sacc[t] = __builtin_amdgcn_mfma_f32_16x16x32_bf16(kf, qf[s], sacc[t], 0, 0, 0);
      }

    // softmax: p = exp2(S'); pack key-pairs to bf16 words
    unsigned pw[4][2];                               // pw[t][i] = keys {16t+4q+2i,+1}
#pragma unroll
    for (int t = 0; t < 4; t++) {
      float p0 = fast_exp2(sacc[t][0]);
      float p1 = fast_exp2(sacc[t][1]);
      float p2 = fast_exp2(sacc[t][2]);
      float p3 = fast_exp2(sacc[t][3]);
      pw[t][0] = cvt_pk_bf16(p0, p1);
      pw[t][1] = cvt_pk_bf16(p2, p3);
    }
    // reg-bit <-> lane-bit5 transposition (pairs differ in t0; lower t first)
    permswap32(pw[0][0], pw[1][0]); permswap32(pw[0][1], pw[1][1]);
    permswap32(pw[2][0], pw[3][0]); permswap32(pw[2][1], pw[3][1]);
    union { unsigned u[4]; short8 s; }
        pf0{{pw[0][0], pw[0][1], pw[1][0], pw[1][1]}},   // s=0 A-frag (permuted keys)
        pf1{{pw[2][0], pw[2][1], pw[3][0], pw[3][1]}};   // s=1 A-frag

    // PV: O += P·V (permuted contraction order); rowsum += P·1
#pragma unroll
    for (int s = 0; s < 2; s++) {
      short8 pf = s ? pf1.s : pf0.s;
      sumacc = __builtin_amdgcn_mfma_f32_16x16x32_bf16(pf, ones, sumacc, 0, 0, 0);
#pragma unroll
      for (int t = 0; t < 4; t++) {
        short8 vf = *(short8*)&Vt[cur][(t * 16 + l16) * 64 + (((quad + 4 * s) ^ (l16 & 7)) << 3)];
        oacc[t] = __builtin_amdgcn_mfma_f32_16x16x32_bf16(pf, vf, oacc[t], 0, 0, 0);
      }
    }
  }

#pragma unroll
  for (int r = 0; r < 4; r++) {                      // O: row q=quad*4+r, col hd=l16
    float inv = 1.0f / sumacc[r];                    // same rows as oacc -> no shuffle
    int row = b * Nc + qrow0 + wv * 16 + quad * 4 + r;
#pragma unroll
    for (int t = 0; t < 4; t++)
      Aout[(size_t)row * Dc + h * HDc + t * 16 + l16] = bf16cast(oacc[t][r] * inv);
  }
}

extern "C" void kernel_launch(void* const* d_in, const int* in_sizes, int n_in,
                              void* d_out, int out_size, void* d_ws, size_t ws_size,
                              hipStream_t stream) {
  const float* q    = (const float*)d_in[0];
  const void*  mask = d_in[1];
  const float* bias = (const float*)d_in[2];
  const float* Wq   = (const float*)d_in[3];
  const float* Wk   = (const float*)d_in[4];
  const float* Wv   = (const float*)d_in[5];
  const float* Wo   = (const float*)d_in[6];
  float* out = (float*)d_out;

  char* ws = (char*)d_ws;
  short* Wqkv = (short*)ws;  ws += (size_t)QKVNc * Dc * 2;
  short* Wob  = (short*)ws;  ws += (size_t)Dc * Dc * 2;
  float* mf   = (float*)ws;  ws += (size_t)Bc * Nc * 4;
  short* QKV  = (short*)ws;  ws += (size_t)Mc * QKVNc * 2;
  short* aout = (short*)ws;  ws += (size_t)Mc * Dc * 2;

  cvtw_kernel<<<dim3(1025), dim3(256), 0, stream>>>(Wq, Wk, Wv, Wo, Wqkv, Wob, mask, mf);

  // Q pre-scaled by 0.125*log2e so attn can use exp2 directly.
  gemm_bt<true, false><<<dim3(QKVNc / 128, Mc / 128), dim3(256), 0, stream>>>(
      (const void*)q, Wqkv, (void*)QKV, Mc, QKVNc, Dc, Dc, 0.125f * L2E);
  attn_kernel<<<dim3(Bc * Hc * 16), dim3(512), 0, stream>>>(QKV, bias, mf, aout);
  gemm_bt<false, true><<<dim3(Dc / 128, Mc / 128), dim3(256), 0, stream>>>(
      (const void*)aout, Wob, (void*)out, Mc, Dc, Dc, 0, 1.0f);
}

// Round 5
// 273.041 us; speedup vs baseline: 1.3176x; 1.0142x over previous
//
#include <hip/hip_runtime.h>
#include <stdint.h>

// MultiHeadAttentionProj: B=4, N=2048, D=512, H=8, HD=64
// cvtw -> maskprep -> GEMM QKV (Q scaled 0.125*log2e) -> flash attn
// (256 thr = 4 waves x 32 q-rows, BM=128, 64-key tiles, S^T form, exp2
//  softmax, mask-only MFMA C-init, bias consumed late in softmax,
//  in-register P via cvt_pk + 2x4 permlane32_swap + V key-permutation,
//  rowsum via MFMA, single-barrier dbuf K/V LDS pitch 64 + chunk XOR swizzle)
// -> GEMM out.
// Rationale: R2/R4 proved the 2-phase loop's wall time is a sum of
// phase-serial pipe bursts; 32 q/wave amortizes every fragment/mask read
// and barrier over 2x the output work.

typedef __attribute__((ext_vector_type(8))) short short8;
typedef __attribute__((ext_vector_type(4))) short short4v;
typedef __attribute__((ext_vector_type(4))) float f32x4;

#define DEV static __device__ __forceinline__

constexpr int Bc = 4, Nc = 2048, Dc = 512, Hc = 8, HDc = 64;
constexpr int Mc = Bc * Nc;        // 8192 rows
constexpr int QKVNc = 3 * Dc;      // 1536
constexpr float L2E = 1.44269504f;

DEV short bf16cast(float f) {      // f32 -> bf16 bits (RNE via HW cvt)
  return (short)__builtin_bit_cast(unsigned short, (__bf16)f);
}
DEV unsigned cvt_pk_bf16(float a, float b) {  // a->low16, b->high16 (RNE)
  unsigned short lb = __builtin_bit_cast(unsigned short, (__bf16)a);
  unsigned short hb = __builtin_bit_cast(unsigned short, (__bf16)b);
  return (unsigned)lb | ((unsigned)hb << 16);
}
DEV unsigned pack_shorts(short a, short b) {
  return (unsigned)(unsigned short)a | ((unsigned)(unsigned short)b << 16);
}
DEV short8 cvt8(float4 a, float4 b) {   // 8 f32 -> short8 bf16
  union { short8 s; uint4 u; } r;
  r.u.x = cvt_pk_bf16(a.x, a.y); r.u.y = cvt_pk_bf16(a.z, a.w);
  r.u.z = cvt_pk_bf16(b.x, b.y); r.u.w = cvt_pk_bf16(b.z, b.w);
  return r.s;
}
DEV float fast_exp2(float x) {
#if __has_builtin(__builtin_amdgcn_exp2f)
  return __builtin_amdgcn_exp2f(x);
#else
  return exp2f(x);
#endif
}
// HW-verified (R3/R4): after op, a = [a.lo32, b.lo32], b = [a.hi32, b.hi32]
DEV void permswap32(unsigned& a, unsigned& b) {
  asm volatile("v_permlane32_swap_b32 %0, %1" : "+v"(a), "+v"(b));
}

// Convert Wq,Wk,Wv -> Wqkv (concat) and Wo -> Wob. 1024 uniform blocks.
__global__ void cvtw_kernel(const float* __restrict__ Wq, const float* __restrict__ Wk,
                            const float* __restrict__ Wv, const float* __restrict__ Wo,
                            short* __restrict__ Wqkv, short* __restrict__ Wob) {
  int which = blockIdx.x >> 8;                       // 4 x 256 blocks
  int j = (blockIdx.x & 255) * 256 + threadIdx.x;    // float4 index < 65536
  const float* src = which == 0 ? Wq : which == 1 ? Wk : which == 2 ? Wv : Wo;
  short* dst = (which == 3) ? Wob : Wqkv + which * (Dc * Dc);
  float4 v = ((const float4*)src)[j];
  short4v o = { bf16cast(v.x), bf16cast(v.y), bf16cast(v.z), bf16cast(v.w) };
  ((short4v*)dst)[j] = o;
}

// Single block: detect mask dtype (int32 vs bool bytes), then convert to
// additive floats. int32 0/1 LE has bytes 1..3 of every word zero.
__global__ void maskprep_kernel(const void* __restrict__ mask, float* __restrict__ mf) {
  __shared__ int flag;
  if (threadIdx.x == 0) flag = 0;
  __syncthreads();
  const uchar4* m4 = (const uchar4*)mask;
  int acc = 0;
  for (int i = threadIdx.x; i < 2048; i += 1024) {
    uchar4 v = m4[i];
    acc |= (int)v.y | (int)v.z | (int)v.w;
  }
  if (acc) atomicOr(&flag, 1);
  __syncthreads();
  int isbyte = flag;
  for (int i = threadIdx.x; i < Bc * Nc; i += 1024) {
    int v = isbyte ? (int)((const unsigned char*)mask)[i] : ((const int*)mask)[i];
    mf[i] = v ? -1e30f : 0.0f;
  }
}

// C[M][N] = sum_k A[m][k]*Bm[n][k]. 128x128 tile, BK=64, rows padded to 72
// shorts; reg-prefetch pipeline. (R0/R1-verified version: single buffer.)
template<bool A_F32, bool OUT_F32>
__global__ __launch_bounds__(256, 2) void gemm_bt(const void* __restrict__ Av,
                                                  const short* __restrict__ Bm,
                                                  void* __restrict__ Cv,
                                                  int M, int N, int K,
                                                  int qcols, float cscale) {
  __shared__ __align__(16) short At[128 * 72];
  __shared__ __align__(16) short Bt[128 * 72];
  const int tid = threadIdx.x, lane = tid & 63, wv = tid >> 6;
  const int quad = lane >> 4, l16 = lane & 15;
  const int mbase = blockIdx.y * 128, nbase = blockIdx.x * 128;
  const int wr = (wv >> 1) * 64, wc = (wv & 1) * 64;
  const float scale = (nbase < qcols) ? cscale : 1.0f;
  f32x4 acc[4][4] = {};
  float4 apf[4][2]; short8 aph[4], bpre[4];
#pragma unroll
  for (int i = 0; i < 4; i++) {                 // preload k0=0
    int flat = i * 256 + tid, row = flat >> 3, ch8 = (flat & 7) * 8;
    if (A_F32) {
      const float* Af = (const float*)Av;
      apf[i][0] = *(const float4*)&Af[(size_t)(mbase + row) * K + ch8];
      apf[i][1] = *(const float4*)&Af[(size_t)(mbase + row) * K + ch8 + 4];
    } else {
      aph[i] = *(const short8*)&((const short*)Av)[(size_t)(mbase + row) * K + ch8];
    }
    bpre[i] = *(const short8*)&Bm[(size_t)(nbase + row) * K + ch8];
  }
  for (int k0 = 0; k0 < K; k0 += 64) {
    __syncthreads();
#pragma unroll
    for (int i = 0; i < 4; i++) {
      int flat = i * 256 + tid, row = flat >> 3, ch8 = (flat & 7) * 8;
      *(short8*)&At[row * 72 + ch8] = A_F32 ? cvt8(apf[i][0], apf[i][1]) : aph[i];
      *(short8*)&Bt[row * 72 + ch8] = bpre[i];
    }
    if (k0 + 64 < K) {
#pragma unroll
      for (int i = 0; i < 4; i++) {             // prefetch next tile
        int flat = i * 256 + tid, row = flat >> 3, ch8 = (flat & 7) * 8;
        if (A_F32) {
          const float* Af = (const float*)Av;
          apf[i][0] = *(const float4*)&Af[(size_t)(mbase + row) * K + k0 + 64 + ch8];
          apf[i][1] = *(const float4*)&Af[(size_t)(mbase + row) * K + k0 + 64 + ch8 + 4];
        } else {
          aph[i] = *(const short8*)&((const short*)Av)[(size_t)(mbase + row) * K + k0 + 64 + ch8];
        }
        bpre[i] = *(const short8*)&Bm[(size_t)(nbase + row) * K + k0 + 64 + ch8];
      }
    }
    __syncthreads();
#pragma unroll
    for (int s = 0; s < 2; s++) {
      short8 af[4], bf[4];
#pragma unroll
      for (int t = 0; t < 4; t++) {
        af[t] = *(short8*)&At[(wr + t * 16 + l16) * 72 + quad * 8 + s * 32];
        bf[t] = *(short8*)&Bt[(wc + t * 16 + l16) * 72 + quad * 8 + s * 32];
      }
#pragma unroll
      for (int mt = 0; mt < 4; mt++)
#pragma unroll
        for (int nt = 0; nt < 4; nt++)
          acc[mt][nt] = __builtin_amdgcn_mfma_f32_16x16x32_bf16(af[mt], bf[nt], acc[mt][nt], 0, 0, 0);
    }
  }
#pragma unroll
  for (int mt = 0; mt < 4; mt++)
#pragma unroll
    for (int nt = 0; nt < 4; nt++)
#pragma unroll
      for (int r = 0; r < 4; r++) {             // C/D: row=quad*4+r, col=l16
        int row = mbase + wr + mt * 16 + quad * 4 + r;
        int col = nbase + wc + nt * 16 + l16;
        float v = acc[mt][nt][r] * scale;
        if (OUT_F32) ((float*)Cv)[(size_t)row * N + col] = v;
        else         ((short*)Cv)[(size_t)row * N + col] = bf16cast(v);
      }
}

// Flash attention, S^T form. BM=128 q-rows, 256 threads = 4 waves x 32 q-rows
// (2 n-tiles of 16 q each), 64-key tiles, single-barrier dbuf K/V LDS
// (pitch 64, chunk^(row&7) swizzle, R4-verified conflict-free).
// C-init = mask (from LDS, broadcast reads). Softmax: p = exp2(fma(bias,L2E,s))
// with bias loaded AFTER the barrier (aged through C-init+QK^T, never drained).
// P in registers via cvt_pk + permlane32_swap + V key-permutation (R4-verified).
// Row-sum via MFMA vs all-ones B.
__global__ __launch_bounds__(256, 2) void attn_kernel(const short* __restrict__ QKV,
                                                      const float* __restrict__ bias,
                                                      const float* __restrict__ maskf,
                                                      short* __restrict__ Aout) {
  __shared__ __align__(16) short Kt[2][64 * 64];     // [key][hd], dbuf, swizzled
  __shared__ __align__(16) short Vt[2][64 * 64];     // [hd][key_perm], dbuf, swizzled
  __shared__ __align__(16) float mlds[Nc];
  const int tid = threadIdx.x, lane = tid & 63, wv = tid >> 6;   // wv 0..3
  const int quad = lane >> 4, l16 = lane & 15;
  const int qt = blockIdx.x & 15, h = (blockIdx.x >> 4) & 7, b = (int)(blockIdx.x >> 7);
  const int qrow0 = qt * 128;
  const int q0 = qrow0 + wv * 32 + l16;              // n=0 q-row; n=1 is q0+16
  const float* biasq0 = bias + ((size_t)b * Nc + q0) * Nc;
  const float* biasq1 = biasq0 + (size_t)16 * Nc;

  ((float4*)mlds)[tid]       = ((const float4*)(maskf + b * Nc))[tid];
  ((float4*)mlds)[tid + 256] = ((const float4*)(maskf + b * Nc))[tid + 256];

  short8 qf[2][2];  // [n][s]: Q (pre-scaled 0.125*log2e), q=n*16+l16, k=quad*8+32s+j
  {
    const short* qp0 = QKV + (size_t)(b * Nc + q0) * QKVNc + h * HDc + quad * 8;
    qf[0][0] = *(const short8*)qp0;
    qf[0][1] = *(const short8*)(qp0 + 32);
    const short* qp1 = qp0 + (size_t)16 * QKVNc;
    qf[1][0] = *(const short8*)qp1;
    qf[1][1] = *(const short8*)(qp1 + 32);
  }

  // staging assignments (256 threads)
  const int krow = tid >> 2, kch0 = (tid & 3) * 2;   // K: row, 2 chunks/thread
  const int kw0 = krow * 64 + ((kch0 ^ (krow & 7)) << 3);
  const int kw1 = krow * 64 + (((kch0 + 1) ^ (krow & 7)) << 3);
  const int vp = tid & 31, vq = tid >> 5;            // V: key-pair, hd-oct 0..7
  const int vperm = (vp & 25) | ((vp & 4) >> 1) | ((vp & 2) << 1);  // key bits 3<->2
  const int vwbase = (((vperm >> 2)) << 3) + 2 * (vperm & 3);       // + hd-dependent XOR
  const short* Kbase = QKV + Dc + h * HDc;
  const short* Vbase = QKV + 2 * Dc + h * HDc;

  short8 kpre0, kpre1, v0pre, v1pre;
  {
    const short* kp = &Kbase[(size_t)(b * Nc + krow) * QKVNc + kch0 * 8];
    kpre0 = *(const short8*)kp;
    kpre1 = *(const short8*)(kp + 8);
    v0pre = *(const short8*)&Vbase[(size_t)(b * Nc + 2 * vp) * QKVNc + vq * 8];
    v1pre = *(const short8*)&Vbase[(size_t)(b * Nc + 2 * vp + 1) * QKVNc + vq * 8];
  }

  const short ONEB = (short)0x3F80;                  // bf16 1.0
  const short8 ones = { ONEB, ONEB, ONEB, ONEB, ONEB, ONEB, ONEB, ONEB };

  f32x4 oacc[2][4] = {};                             // [m][t]: row q=m*16+quad*4+r, col hd=16t+l16
  f32x4 sumacc[2] = {};                              // rowsum per m-tile

  for (int kt = 0; kt < 32; kt++) {
    const int cur = kt & 1;
    const int kb = kt * 64;
    const int kbn = ((kt + 1) & 31) * 64;            // next tile (wraps, in-bounds)

    // W: regs -> LDS buf[cur] (swizzled)
    *(short8*)&Kt[cur][kw0] = kpre0;
    *(short8*)&Kt[cur][kw1] = kpre1;
#pragma unroll
    for (int j = 0; j < 8; j++) {                    // V -> LDS transposed (b32)
      int hd = vq * 8 + j;
      *(unsigned*)&Vt[cur][hd * 64 + (vwbase ^ ((hd & 7) << 3))] =
          pack_shorts(v0pre[j], v1pre[j]);
    }
    __syncthreads();                                 // ONE barrier per tile

    // issue loads AFTER the barrier (never drained): K/V for kt+1, bias for kt
    {
      const short* kp = &Kbase[(size_t)(b * Nc + kbn + krow) * QKVNc + kch0 * 8];
      kpre0 = *(const short8*)kp;
      kpre1 = *(const short8*)(kp + 8);
      v0pre = *(const short8*)&Vbase[(size_t)(b * Nc + kbn + 2 * vp) * QKVNc + vq * 8];
      v1pre = *(const short8*)&Vbase[(size_t)(b * Nc + kbn + 2 * vp + 1) * QKVNc + vq * 8];
    }
    float4 bb[2][4];
#pragma unroll
    for (int t = 0; t < 4; t++) {                    // bias: consumed in softmax
      bb[0][t] = *(const float4*)&biasq0[kb + t * 16 + quad * 4];
      bb[1][t] = *(const float4*)&biasq1[kb + t * 16 + quad * 4];
    }

    // C-init = mask (broadcast LDS reads; same for both n-tiles)
    f32x4 sacc[2][4];
#pragma unroll
    for (int t = 0; t < 4; t++) {
      float4 mv = *(const float4*)&mlds[kb + t * 16 + quad * 4];
      sacc[0][t][0] = mv.x; sacc[0][t][1] = mv.y; sacc[0][t][2] = mv.z; sacc[0][t][3] = mv.w;
      sacc[1][t] = sacc[0][t];
    }

    // QK^T: S^T[key=16t+4quad+r][q=n*16+l16]; kf shared across n
#pragma unroll
    for (int s = 0; s < 2; s++)
#pragma unroll
      for (int t = 0; t < 4; t++) {
        short8 kf = *(short8*)&Kt[cur][(t * 16 + l16) * 64 + (((quad + 4 * s) ^ (l16 & 7)) << 3)];
        sacc[0][t] = __builtin_amdgcn_mfma_f32_16x16x32_bf16(kf, qf[0][s], sacc[0][t], 0, 0, 0);
        sacc[1][t] = __builtin_amdgcn_mfma_f32_16x16x32_bf16(kf, qf[1][s], sacc[1][t], 0, 0, 0);
      }

    // softmax: p = exp2(bias*log2e + s_with_mask); pack; permute to A-frags
    short8 pf[2][2];
#pragma unroll
    for (int n = 0; n < 2; n++) {
      unsigned pw[4][2];
#pragma unroll
      for (int t = 0; t < 4; t++) {
        float p0 = fast_exp2(__builtin_fmaf(bb[n][t].x, L2E, sacc[n][t][0]));
        float p1 = fast_exp2(__builtin_fmaf(bb[n][t].y, L2E, sacc[n][t][1]));
        float p2 = fast_exp2(__builtin_fmaf(bb[n][t].z, L2E, sacc[n][t][2]));
        float p3 = fast_exp2(__builtin_fmaf(bb[n][t].w, L2E, sacc[n][t][3]));
        pw[t][0] = cvt_pk_bf16(p0, p1);
        pw[t][1] = cvt_pk_bf16(p2, p3);
      }
      permswap32(pw[0][0], pw[1][0]); permswap32(pw[0][1], pw[1][1]);
      permswap32(pw[2][0], pw[3][0]); permswap32(pw[2][1], pw[3][1]);
      union { unsigned u[4]; short8 s; }
          a0{{pw[0][0], pw[0][1], pw[1][0], pw[1][1]}},
          a1{{pw[2][0], pw[2][1], pw[3][0], pw[3][1]}};
      pf[n][0] = a0.s; pf[n][1] = a1.s;
    }

    // PV: O += P·V (permuted contraction, matches Vt layout); rowsum += P·1
#pragma unroll
    for (int s = 0; s < 2; s++) {
      sumacc[0] = __builtin_amdgcn_mfma_f32_16x16x32_bf16(pf[0][s], ones, sumacc[0], 0, 0, 0);
      sumacc[1] = __builtin_amdgcn_mfma_f32_16x16x32_bf16(pf[1][s], ones, sumacc[1], 0, 0, 0);
#pragma unroll
      for (int t = 0; t < 4; t++) {
        short8 vf = *(short8*)&Vt[cur][(t * 16 + l16) * 64 + (((quad + 4 * s) ^ (l16 & 7)) << 3)];
        oacc[0][t] = __builtin_amdgcn_mfma_f32_16x16x32_bf16(pf[0][s], vf, oacc[0][t], 0, 0, 0);
        oacc[1][t] = __builtin_amdgcn_mfma_f32_16x16x32_bf16(pf[1][s], vf, oacc[1][t], 0, 0, 0);
      }
    }
  }

#pragma unroll
  for (int m = 0; m < 2; m++)
#pragma unroll
    for (int r = 0; r < 4; r++) {                    // O row q=m*16+quad*4+r, col hd=16t+l16
      float inv = 1.0f / sumacc[m][r];
      int row = b * Nc + qrow0 + wv * 32 + m * 16 + quad * 4 + r;
#pragma unroll
      for (int t = 0; t < 4; t++)
        Aout[(size_t)row * Dc + h * HDc + t * 16 + l16] = bf16cast(oacc[m][t][r] * inv);
    }
}

extern "C" void kernel_launch(void* const* d_in, const int* in_sizes, int n_in,
                              void* d_out, int out_size, void* d_ws, size_t ws_size,
                              hipStream_t stream) {
  const float* q    = (const float*)d_in[0];
  const void*  mask = d_in[1];
  const float* bias = (const float*)d_in[2];
  const float* Wq   = (const float*)d_in[3];
  const float* Wk   = (const float*)d_in[4];
  const float* Wv   = (const float*)d_in[5];
  const float* Wo   = (const float*)d_in[6];
  float* out = (float*)d_out;

  char* ws = (char*)d_ws;
  short* Wqkv = (short*)ws;  ws += (size_t)QKVNc * Dc * 2;
  short* Wob  = (short*)ws;  ws += (size_t)Dc * Dc * 2;
  float* mf   = (float*)ws;  ws += (size_t)Bc * Nc * 4;
  short* QKV  = (short*)ws;  ws += (size_t)Mc * QKVNc * 2;
  short* aout = (short*)ws;  ws += (size_t)Mc * Dc * 2;

  cvtw_kernel<<<dim3(1024), dim3(256), 0, stream>>>(Wq, Wk, Wv, Wo, Wqkv, Wob);
  maskprep_kernel<<<dim3(1), dim3(1024), 0, stream>>>(mask, mf);

  // Q pre-scaled by 0.125*log2e so attn can use exp2 directly.
  gemm_bt<true, false><<<dim3(QKVNc / 128, Mc / 128), dim3(256), 0, stream>>>(
      (const void*)q, Wqkv, (void*)QKV, Mc, QKVNc, Dc, Dc, 0.125f * L2E);
  attn_kernel<<<dim3(Bc * Hc * 16), dim3(256), 0, stream>>>(QKV, bias, mf, aout);
  gemm_bt<false, true><<<dim3(Dc / 128, Mc / 128), dim3(256), 0, stream>>>(
      (const void*)aout, Wob, (void*)out, Mc, Dc, Dc, 0, 1.0f);
}

// Round 6
// 269.531 us; speedup vs baseline: 1.3348x; 1.0130x over previous
//
#include <hip/hip_runtime.h>
#include <stdint.h>

// MultiHeadAttentionProj: B=4, N=2048, D=512, H=8, HD=64
// cvtw (W->bf16 concat, q->bf16, maskprep fused) -> GEMM QKV (global_load_lds
// m97-structure, 128x128, 3 blocks/CU, Q cols scaled 0.125*log2e in epilogue)
// -> flash attn (UNCHANGED from R5: 4 waves x 32 q-rows, in-register P,
//    conflict-free swizzled LDS, exp2 softmax, MFMA rowsum)
// -> GEMM out (global_load_lds, 128x64 tiles, 512 blocks).
// GEMM staging: linear LDS dest + per-lane XOR-pre-swizzled global source
// (chunk ^= row&7), swizzled read side verified correct in R3/R4.

typedef __attribute__((ext_vector_type(8))) short short8;
typedef __attribute__((ext_vector_type(4))) short short4v;
typedef __attribute__((ext_vector_type(4))) float f32x4;

#define DEV static __device__ __forceinline__

constexpr int Bc = 4, Nc = 2048, Dc = 512, Hc = 8, HDc = 64;
constexpr int Mc = Bc * Nc;        // 8192 rows
constexpr int QKVNc = 3 * Dc;      // 1536
constexpr float L2E = 1.44269504f;

DEV short bf16cast(float f) {      // f32 -> bf16 bits (RNE via HW cvt)
  return (short)__builtin_bit_cast(unsigned short, (__bf16)f);
}
DEV unsigned cvt_pk_bf16(float a, float b) {  // a->low16, b->high16 (RNE)
  unsigned short lb = __builtin_bit_cast(unsigned short, (__bf16)a);
  unsigned short hb = __builtin_bit_cast(unsigned short, (__bf16)b);
  return (unsigned)lb | ((unsigned)hb << 16);
}
DEV unsigned pack_shorts(short a, short b) {
  return (unsigned)(unsigned short)a | ((unsigned)(unsigned short)b << 16);
}
DEV float fast_exp2(float x) {
#if __has_builtin(__builtin_amdgcn_exp2f)
  return __builtin_amdgcn_exp2f(x);
#else
  return exp2f(x);
#endif
}
// HW-verified (R3/R4): after op, a = [a.lo32, b.lo32], b = [a.hi32, b.hi32]
DEV void permswap32(unsigned& a, unsigned& b) {
  asm volatile("v_permlane32_swap_b32 %0, %1" : "+v"(a), "+v"(b));
}
// async global->LDS, 16B per lane; LDS dest = wave-uniform base + lane*16
DEV void gl_lds16(const short* g, short* l) {
  __builtin_amdgcn_global_load_lds(
      (const __attribute__((address_space(1))) void*)g,
      (__attribute__((address_space(3))) void*)l, 16, 0, 0);
}

// Blocks 0..1023: Wq,Wk,Wv -> Wqkv (concat), Wo -> Wob.
// Blocks 1024..5119: q (f32) -> qb (bf16).
// Block 5120: maskprep (detect dtype, convert to additive floats).
__global__ void cvtw_kernel(const float* __restrict__ Wq, const float* __restrict__ Wk,
                            const float* __restrict__ Wv, const float* __restrict__ Wo,
                            const float* __restrict__ q,
                            short* __restrict__ Wqkv, short* __restrict__ Wob,
                            short* __restrict__ qb,
                            const void* __restrict__ mask, float* __restrict__ mf) {
  int bid = blockIdx.x;
  if (bid >= 5120) {                                 // fused maskprep, 256 threads
    __shared__ int flag;
    if (threadIdx.x == 0) flag = 0;
    __syncthreads();
    const uchar4* m4 = (const uchar4*)mask;
    int acc = 0;
    for (int i = threadIdx.x; i < 2048; i += 256) {
      uchar4 v = m4[i];
      acc |= (int)v.y | (int)v.z | (int)v.w;
    }
    if (acc) atomicOr(&flag, 1);
    __syncthreads();
    int isbyte = flag;                               // int32 0/1 has bytes 1..3 zero
    for (int i = threadIdx.x; i < Bc * Nc; i += 256) {
      int v = isbyte ? (int)((const unsigned char*)mask)[i] : ((const int*)mask)[i];
      mf[i] = v ? -1e30f : 0.0f;
    }
    return;
  }
  const float* src; short* dst; int j;
  if (bid < 1024) {                                  // weights: 4 x 256 blocks
    int which = bid >> 8;
    j = (bid & 255) * 256 + threadIdx.x;             // float4 index < 65536
    src = which == 0 ? Wq : which == 1 ? Wk : which == 2 ? Wv : Wo;
    dst = (which == 3) ? Wob : Wqkv + which * (Dc * Dc);
  } else {                                           // q: 4096 blocks
    j = (bid - 1024) * 256 + threadIdx.x;            // float4 index < 1048576
    src = q; dst = qb;
  }
  float4 v = ((const float4*)src)[j];
  short4v o = { bf16cast(v.x), bf16cast(v.y), bf16cast(v.z), bf16cast(v.w) };
  ((short4v*)dst)[j] = o;
}

// C[M][N] = sum_k A[m][k]*Bm[n][k], A/B bf16. m97 structure: 128xBN tile,
// BK=64, global_load_lds (16B) staging with linear LDS + per-lane XOR-swizzled
// global source (chunk ^= row&7); swizzled conflict-free b128 frag reads.
// BN=128: 4 waves as 2x2 of 64x64 (acc 4x4). BN=64: 4 waves as 4x1 of 32x64
// (acc 2x4). 2 barriers per K-step, no reg prefetch.
template<int BN, bool OUT_F32, int MINW>
__global__ __launch_bounds__(256, MINW) void gemm_bt(const short* __restrict__ A,
                                                     const short* __restrict__ Bm,
                                                     void* __restrict__ Cv,
                                                     int M, int N, int K,
                                                     int qcols, float cscale) {
  constexpr int MT = (BN == 128) ? 4 : 2;
  constexpr int NT = 4;
  __shared__ __align__(16) short At[128 * 64];
  __shared__ __align__(16) short Bt[BN * 64];
  const int tid = threadIdx.x, lane = tid & 63, wv = tid >> 6;
  const int quad = lane >> 4, l16 = lane & 15;
  const int mbase = blockIdx.y * 128, nbase = blockIdx.x * BN;
  const int wr = (BN == 128) ? (wv >> 1) * 64 : wv * 32;
  const int wc = (BN == 128) ? (wv & 1) * 64 : 0;
  const float scale = (nbase < qcols) ? cscale : 1.0f;
  f32x4 acc[MT][NT] = {};

  for (int k0 = 0; k0 < K; k0 += 64) {
    // stage A: 128 rows x 64 shorts; 4 gload_lds per wave (1 KB each)
#pragma unroll
    for (int i = 0; i < 4; i++) {
      int ibase = (wv * 4 + i) * 64;                 // chunk index base
      int row = (ibase + lane) >> 3, c = lane & 7;
      gl_lds16(&A[(size_t)(mbase + row) * K + k0 + ((c ^ (row & 7)) << 3)],
               &At[ibase << 3]);
    }
    // stage B: BN rows; BN/32 gload_lds per wave
#pragma unroll
    for (int i = 0; i < BN / 32; i++) {
      int ibase = (wv * (BN / 32) + i) * 64;
      int row = (ibase + lane) >> 3, c = lane & 7;
      gl_lds16(&Bm[(size_t)(nbase + row) * K + k0 + ((c ^ (row & 7)) << 3)],
               &Bt[ibase << 3]);
    }
    __syncthreads();                                 // drains vmcnt: tiles ready
#pragma unroll
    for (int s = 0; s < 2; s++) {
      short8 af[MT], bf[NT];
#pragma unroll
      for (int t = 0; t < MT; t++) {
        int r = wr + t * 16 + l16;
        af[t] = *(short8*)&At[r * 64 + (((quad + 4 * s) ^ (r & 7)) << 3)];
      }
#pragma unroll
      for (int t = 0; t < NT; t++) {
        int r = wc + t * 16 + l16;
        bf[t] = *(short8*)&Bt[r * 64 + (((quad + 4 * s) ^ (r & 7)) << 3)];
      }
#pragma unroll
      for (int mt = 0; mt < MT; mt++)
#pragma unroll
        for (int nt = 0; nt < NT; nt++)
          acc[mt][nt] = __builtin_amdgcn_mfma_f32_16x16x32_bf16(af[mt], bf[nt], acc[mt][nt], 0, 0, 0);
    }
    __syncthreads();                                 // reads done before next stage
  }
#pragma unroll
  for (int mt = 0; mt < MT; mt++)
#pragma unroll
    for (int nt = 0; nt < NT; nt++)
#pragma unroll
      for (int r = 0; r < 4; r++) {                  // C/D: row=quad*4+r, col=l16
        int row = mbase + wr + mt * 16 + quad * 4 + r;
        int col = nbase + wc + nt * 16 + l16;
        float v = acc[mt][nt][r] * scale;
        if (OUT_F32) ((float*)Cv)[(size_t)row * N + col] = v;
        else         ((short*)Cv)[(size_t)row * N + col] = bf16cast(v);
      }
}

// Flash attention — UNCHANGED from R5 (control). S^T form, BM=128, 256 thr =
// 4 waves x 32 q-rows, 64-key tiles, single-barrier dbuf K/V LDS (pitch 64,
// chunk^(row&7) swizzle, conflict-free). C-init = mask; p = exp2(fma(bias,L2E,s));
// P in registers via cvt_pk + permlane32_swap + V key-permutation; MFMA rowsum.
__global__ __launch_bounds__(256, 2) void attn_kernel(const short* __restrict__ QKV,
                                                      const float* __restrict__ bias,
                                                      const float* __restrict__ maskf,
                                                      short* __restrict__ Aout) {
  __shared__ __align__(16) short Kt[2][64 * 64];     // [key][hd], dbuf, swizzled
  __shared__ __align__(16) short Vt[2][64 * 64];     // [hd][key_perm], dbuf, swizzled
  __shared__ __align__(16) float mlds[Nc];
  const int tid = threadIdx.x, lane = tid & 63, wv = tid >> 6;   // wv 0..3
  const int quad = lane >> 4, l16 = lane & 15;
  const int qt = blockIdx.x & 15, h = (blockIdx.x >> 4) & 7, b = (int)(blockIdx.x >> 7);
  const int qrow0 = qt * 128;
  const int q0 = qrow0 + wv * 32 + l16;              // n=0 q-row; n=1 is q0+16
  const float* biasq0 = bias + ((size_t)b * Nc + q0) * Nc;
  const float* biasq1 = biasq0 + (size_t)16 * Nc;

  ((float4*)mlds)[tid]       = ((const float4*)(maskf + b * Nc))[tid];
  ((float4*)mlds)[tid + 256] = ((const float4*)(maskf + b * Nc))[tid + 256];

  short8 qf[2][2];  // [n][s]: Q (pre-scaled 0.125*log2e), q=n*16+l16, k=quad*8+32s+j
  {
    const short* qp0 = QKV + (size_t)(b * Nc + q0) * QKVNc + h * HDc + quad * 8;
    qf[0][0] = *(const short8*)qp0;
    qf[0][1] = *(const short8*)(qp0 + 32);
    const short* qp1 = qp0 + (size_t)16 * QKVNc;
    qf[1][0] = *(const short8*)qp1;
    qf[1][1] = *(const short8*)(qp1 + 32);
  }

  // staging assignments (256 threads)
  const int krow = tid >> 2, kch0 = (tid & 3) * 2;   // K: row, 2 chunks/thread
  const int kw0 = krow * 64 + ((kch0 ^ (krow & 7)) << 3);
  const int kw1 = krow * 64 + (((kch0 + 1) ^ (krow & 7)) << 3);
  const int vp = tid & 31, vq = tid >> 5;            // V: key-pair, hd-oct 0..7
  const int vperm = (vp & 25) | ((vp & 4) >> 1) | ((vp & 2) << 1);  // key bits 3<->2
  const int vwbase = (((vperm >> 2)) << 3) + 2 * (vperm & 3);       // + hd-dependent XOR
  const short* Kbase = QKV + Dc + h * HDc;
  const short* Vbase = QKV + 2 * Dc + h * HDc;

  short8 kpre0, kpre1, v0pre, v1pre;
  {
    const short* kp = &Kbase[(size_t)(b * Nc + krow) * QKVNc + kch0 * 8];
    kpre0 = *(const short8*)kp;
    kpre1 = *(const short8*)(kp + 8);
    v0pre = *(const short8*)&Vbase[(size_t)(b * Nc + 2 * vp) * QKVNc + vq * 8];
    v1pre = *(const short8*)&Vbase[(size_t)(b * Nc + 2 * vp + 1) * QKVNc + vq * 8];
  }

  const short ONEB = (short)0x3F80;                  // bf16 1.0
  const short8 ones = { ONEB, ONEB, ONEB, ONEB, ONEB, ONEB, ONEB, ONEB };

  f32x4 oacc[2][4] = {};                             // [m][t]: row q=m*16+quad*4+r, col hd=16t+l16
  f32x4 sumacc[2] = {};                              // rowsum per m-tile

  for (int kt = 0; kt < 32; kt++) {
    const int cur = kt & 1;
    const int kb = kt * 64;
    const int kbn = ((kt + 1) & 31) * 64;            // next tile (wraps, in-bounds)

    // W: regs -> LDS buf[cur] (swizzled)
    *(short8*)&Kt[cur][kw0] = kpre0;
    *(short8*)&Kt[cur][kw1] = kpre1;
#pragma unroll
    for (int j = 0; j < 8; j++) {                    // V -> LDS transposed (b32)
      int hd = vq * 8 + j;
      *(unsigned*)&Vt[cur][hd * 64 + (vwbase ^ ((hd & 7) << 3))] =
          pack_shorts(v0pre[j], v1pre[j]);
    }
    __syncthreads();                                 // ONE barrier per tile

    // issue loads AFTER the barrier (never drained): K/V for kt+1, bias for kt
    {
      const short* kp = &Kbase[(size_t)(b * Nc + kbn + krow) * QKVNc + kch0 * 8];
      kpre0 = *(const short8*)kp;
      kpre1 = *(const short8*)(kp + 8);
      v0pre = *(const short8*)&Vbase[(size_t)(b * Nc + kbn + 2 * vp) * QKVNc + vq * 8];
      v1pre = *(const short8*)&Vbase[(size_t)(b * Nc + kbn + 2 * vp + 1) * QKVNc + vq * 8];
    }
    float4 bb[2][4];
#pragma unroll
    for (int t = 0; t < 4; t++) {                    // bias: consumed in softmax
      bb[0][t] = *(const float4*)&biasq0[kb + t * 16 + quad * 4];
      bb[1][t] = *(const float4*)&biasq1[kb + t * 16 + quad * 4];
    }

    // C-init = mask (broadcast LDS reads; same for both n-tiles)
    f32x4 sacc[2][4];
#pragma unroll
    for (int t = 0; t < 4; t++) {
      float4 mv = *(const float4*)&mlds[kb + t * 16 + quad * 4];
      sacc[0][t][0] = mv.x; sacc[0][t][1] = mv.y; sacc[0][t][2] = mv.z; sacc[0][t][3] = mv.w;
      sacc[1][t] = sacc[0][t];
    }

    // QK^T: S^T[key=16t+4quad+r][q=n*16+l16]; kf shared across n
#pragma unroll
    for (int s = 0; s < 2; s++)
#pragma unroll
      for (int t = 0; t < 4; t++) {
        short8 kf = *(short8*)&Kt[cur][(t * 16 + l16) * 64 + (((quad + 4 * s) ^ (l16 & 7)) << 3)];
        sacc[0][t] = __builtin_amdgcn_mfma_f32_16x16x32_bf16(kf, qf[0][s], sacc[0][t], 0, 0, 0);
        sacc[1][t] = __builtin_amdgcn_mfma_f32_16x16x32_bf16(kf, qf[1][s], sacc[1][t], 0, 0, 0);
      }

    // softmax: p = exp2(bias*log2e + s_with_mask); pack; permute to A-frags
    short8 pf[2][2];
#pragma unroll
    for (int n = 0; n < 2; n++) {
      unsigned pw[4][2];
#pragma unroll
      for (int t = 0; t < 4; t++) {
        float p0 = fast_exp2(__builtin_fmaf(bb[n][t].x, L2E, sacc[n][t][0]));
        float p1 = fast_exp2(__builtin_fmaf(bb[n][t].y, L2E, sacc[n][t][1]));
        float p2 = fast_exp2(__builtin_fmaf(bb[n][t].z, L2E, sacc[n][t][2]));
        float p3 = fast_exp2(__builtin_fmaf(bb[n][t].w, L2E, sacc[n][t][3]));
        pw[t][0] = cvt_pk_bf16(p0, p1);
        pw[t][1] = cvt_pk_bf16(p2, p3);
      }
      permswap32(pw[0][0], pw[1][0]); permswap32(pw[0][1], pw[1][1]);
      permswap32(pw[2][0], pw[3][0]); permswap32(pw[2][1], pw[3][1]);
      union { unsigned u[4]; short8 s; }
          a0{{pw[0][0], pw[0][1], pw[1][0], pw[1][1]}},
          a1{{pw[2][0], pw[2][1], pw[3][0], pw[3][1]}};
      pf[n][0] = a0.s; pf[n][1] = a1.s;
    }

    // PV: O += P·V (permuted contraction, matches Vt layout); rowsum += P·1
#pragma unroll
    for (int s = 0; s < 2; s++) {
      sumacc[0] = __builtin_amdgcn_mfma_f32_16x16x32_bf16(pf[0][s], ones, sumacc[0], 0, 0, 0);
      sumacc[1] = __builtin_amdgcn_mfma_f32_16x16x32_bf16(pf[1][s], ones, sumacc[1], 0, 0, 0);
#pragma unroll
      for (int t = 0; t < 4; t++) {
        short8 vf = *(short8*)&Vt[cur][(t * 16 + l16) * 64 + (((quad + 4 * s) ^ (l16 & 7)) << 3)];
        oacc[0][t] = __builtin_amdgcn_mfma_f32_16x16x32_bf16(pf[0][s], vf, oacc[0][t], 0, 0, 0);
        oacc[1][t] = __builtin_amdgcn_mfma_f32_16x16x32_bf16(pf[1][s], vf, oacc[1][t], 0, 0, 0);
      }
    }
  }

#pragma unroll
  for (int m = 0; m < 2; m++)
#pragma unroll
    for (int r = 0; r < 4; r++) {                    // O row q=m*16+quad*4+r, col hd=16t+l16
      float inv = 1.0f / sumacc[m][r];
      int row = b * Nc + qrow0 + wv * 32 + m * 16 + quad * 4 + r;
#pragma unroll
      for (int t = 0; t < 4; t++)
        Aout[(size_t)row * Dc + h * HDc + t * 16 + l16] = bf16cast(oacc[m][t][r] * inv);
    }
}

extern "C" void kernel_launch(void* const* d_in, const int* in_sizes, int n_in,
                              void* d_out, int out_size, void* d_ws, size_t ws_size,
                              hipStream_t stream) {
  const float* q    = (const float*)d_in[0];
  const void*  mask = d_in[1];
  const float* bias = (const float*)d_in[2];
  const float* Wq   = (const float*)d_in[3];
  const float* Wk   = (const float*)d_in[4];
  const float* Wv   = (const float*)d_in[5];
  const float* Wo   = (const float*)d_in[6];
  float* out = (float*)d_out;

  char* ws = (char*)d_ws;
  short* Wqkv = (short*)ws;  ws += (size_t)QKVNc * Dc * 2;
  short* Wob  = (short*)ws;  ws += (size_t)Dc * Dc * 2;
  float* mf   = (float*)ws;  ws += (size_t)Bc * Nc * 4;
  short* QKV  = (short*)ws;  ws += (size_t)Mc * QKVNc * 2;
  short* aout = (short*)ws;  ws += (size_t)Mc * Dc * 2;
  short* qb   = (short*)ws;  ws += (size_t)Mc * Dc * 2;

  cvtw_kernel<<<dim3(5121), dim3(256), 0, stream>>>(Wq, Wk, Wv, Wo, q, Wqkv, Wob, qb, mask, mf);

  // Q pre-scaled (epilogue) by 0.125*log2e so attn can use exp2 directly.
  gemm_bt<128, false, 3><<<dim3(QKVNc / 128, Mc / 128), dim3(256), 0, stream>>>(
      qb, Wqkv, (void*)QKV, Mc, QKVNc, Dc, Dc, 0.125f * L2E);
  attn_kernel<<<dim3(Bc * Hc * 16), dim3(256), 0, stream>>>(QKV, bias, mf, aout);
  gemm_bt<64, true, 4><<<dim3(Dc / 64, Mc / 128), dim3(256), 0, stream>>>(
      aout, Wob, (void*)out, Mc, Dc, Dc, 0, 1.0f);
}